// Round 5
// baseline (133.431 us; speedup 1.0000x reference)
//
#include <hip/hip_runtime.h>
#include <math.h>

namespace {

constexpr int BLK   = 256;
constexpr int SEQ   = 4;
constexpr int CHUNK = BLK * SEQ; // 1024
constexpr int NWAVE = BLK / 64;  // 4

struct V3 { float x, y, z; };
struct Q4 { float x, y, z, w; };
struct St { Q4 q; V3 s; V3 p; float T; float pad; }; // 48 B

__device__ __forceinline__ Q4 qmul(const Q4 a, const Q4 b) {
  Q4 r;
  r.x = a.w*b.x + b.w*a.x + a.y*b.z - a.z*b.y;
  r.y = a.w*b.y + b.w*a.y + a.z*b.x - a.x*b.z;
  r.z = a.w*b.z + b.w*a.z + a.x*b.y - a.y*b.x;
  r.w = a.w*b.w - a.x*b.x - a.y*b.y - a.z*b.z;
  return r;
}

__device__ __forceinline__ V3 qrot(const Q4 q, const V3 v) {
  float tx = q.y*v.z - q.z*v.y + q.w*v.x;
  float ty = q.z*v.x - q.x*v.z + q.w*v.y;
  float tz = q.x*v.y - q.y*v.x + q.w*v.z;
  V3 r;
  r.x = v.x + 2.0f*(q.y*tz - q.z*ty);
  r.y = v.y + 2.0f*(q.z*tx - q.x*tz);
  r.z = v.z + 2.0f*(q.x*ty - q.y*tx);
  return r;
}

__device__ __forceinline__ St combine(const St a, const St b) {
  St r;
  r.q = qmul(a.q, b.q);
  V3 rs = qrot(a.q, b.s);
  r.s.x = a.s.x + rs.x;
  r.s.y = a.s.y + rs.y;
  r.s.z = a.s.z + rs.z;
  V3 rp = qrot(a.q, b.p);
  r.p.x = a.p.x + a.s.x*b.T + rp.x;
  r.p.y = a.p.y + a.s.y*b.T + rp.y;
  r.p.z = a.p.z + a.s.z*b.T + rp.z;
  r.T = a.T + b.T;
  r.pad = 0.0f;
  return r;
}

__device__ __forceinline__ St identity_st() {
  St r;
  r.q = {0.0f, 0.0f, 0.0f, 1.0f};
  r.s = {0.0f, 0.0f, 0.0f};
  r.p = {0.0f, 0.0f, 0.0f};
  r.T = 0.0f; r.pad = 0.0f;
  return r;
}

// θ = |gyro*dt| ≤ ~0.02 here: 2-term Taylor in θ² is fp32-exact. No libm.
__device__ __forceinline__ St elem_state(float dt, V3 w, V3 ac, Q4 gt) {
  float px = w.x*dt, py = w.y*dt, pz = w.z*dt;
  float t2 = px*px + py*py + pz*pz;                        // θ²
  float k  = 0.5f + t2*(-1.0f/48.0f  + t2*(1.0f/3840.0f)); // sin(θ/2)/θ
  float cw = 1.0f + t2*(-0.125f      + t2*(1.0f/384.0f));  // cos(θ/2)
  Q4 dr = { px*k, py*k, pz*k, cw };
  Q4 gi = { -gt.x, -gt.y, -gt.z, gt.w };
  V3 g  = { 0.0f, 0.0f, 9.81007f };
  V3 gr = qrot(gi, g);
  V3 a  = { ac.x - gr.x, ac.y - gr.y, ac.z - gr.z };
  V3 ra = qrot(dr, a);
  St e;
  e.q = dr;
  e.s.x = ra.x*dt; e.s.y = ra.y*dt; e.s.z = ra.z*dt;
  float h = 0.5f*dt;
  e.p.x = e.s.x*h; e.p.y = e.s.y*h; e.p.z = e.s.z*h;
  e.T = dt; e.pad = 0.0f;
  return e;
}

__device__ __forceinline__ St shfl_up_st(const St& v, int d) {
  St r;
  r.q.x = __shfl_up(v.q.x, d); r.q.y = __shfl_up(v.q.y, d);
  r.q.z = __shfl_up(v.q.z, d); r.q.w = __shfl_up(v.q.w, d);
  r.s.x = __shfl_up(v.s.x, d); r.s.y = __shfl_up(v.s.y, d);
  r.s.z = __shfl_up(v.s.z, d);
  r.p.x = __shfl_up(v.p.x, d); r.p.y = __shfl_up(v.p.y, d);
  r.p.z = __shfl_up(v.p.z, d);
  r.T   = __shfl_up(v.T, d);   r.pad = 0.0f;
  return r;
}

__device__ __forceinline__ St shfl_down_st(const St& v, int d) {
  St r;
  r.q.x = __shfl_down(v.q.x, d); r.q.y = __shfl_down(v.q.y, d);
  r.q.z = __shfl_down(v.q.z, d); r.q.w = __shfl_down(v.q.w, d);
  r.s.x = __shfl_down(v.s.x, d); r.s.y = __shfl_down(v.s.y, d);
  r.s.z = __shfl_down(v.s.z, d);
  r.p.x = __shfl_down(v.p.x, d); r.p.y = __shfl_down(v.p.y, d);
  r.p.z = __shfl_down(v.p.z, d);
  r.T   = __shfl_down(v.T, d);   r.pad = 0.0f;
  return r;
}

// St <-> 3x float4 (memory layout: q.xyzw | s.xyz p.x | p.yz T pad)
__device__ __forceinline__ St ld_st3(const float4* p) {
  float4 a = p[0], b = p[1], c = p[2];
  St r;
  r.q = {a.x, a.y, a.z, a.w};
  r.s = {b.x, b.y, b.z};
  r.p = {b.w, c.x, c.y};
  r.T = c.z; r.pad = 0.0f;
  return r;
}
__device__ __forceinline__ void st_st3(float4* p, const St& v) {
  p[0] = make_float4(v.q.x, v.q.y, v.q.z, v.q.w);
  p[1] = make_float4(v.s.x, v.s.y, v.s.z, v.p.x);
  p[2] = make_float4(v.p.y, v.p.z, v.T, 0.0f);
}

// Load SEQ=4 elements' inputs and build the 4 element states in registers.
#define BUILD_ELEMS(E)                                                         \
  St E[SEQ];                                                                   \
  {                                                                            \
    float dtv[SEQ]; float gy[SEQ*3]; float acv[SEQ*3]; float gq[SEQ*4];        \
    *((float4*)dtv) = *(const float4*)(dtp + gi);                              \
    _Pragma("unroll")                                                          \
    for (int j = 0; j < 3; ++j) ((float4*)gy)[j]  = ((const float4*)(gyp + gi*3))[j]; \
    _Pragma("unroll")                                                          \
    for (int j = 0; j < 3; ++j) ((float4*)acv)[j] = ((const float4*)(acp + gi*3))[j]; \
    _Pragma("unroll")                                                          \
    for (int j = 0; j < 4; ++j) ((float4*)gq)[j]  = ((const float4*)(gtp + gi*4))[j]; \
    _Pragma("unroll")                                                          \
    for (int i = 0; i < SEQ; ++i)                                              \
      E[i] = elem_state(dtv[i],                                                \
                 {gy[3*i], gy[3*i+1], gy[3*i+2]},                              \
                 {acv[3*i], acv[3*i+1], acv[3*i+2]},                           \
                 {gq[4*i], gq[4*i+1], gq[4*i+2], gq[4*i+3]});                  \
  }

// Single-pass scan with deterministic decoupled lookback.
// Virtual tile ids from an atomic ticket => ticket order == start order =>
// all predecessors of a tile are started (resident) => no deadlock.
// Row-first tiles publish seed∘agg; others publish raw agg. Lookback always
// composes pref(lo) ∘ agg(lo+1) ∘ ... ∘ agg(t-1): fixed association,
// bitwise deterministic regardless of timing.
__global__ __launch_bounds__(BLK) void k_fused(
    const float* __restrict__ dtp, const float* __restrict__ gyp,
    const float* __restrict__ acp, const float* __restrict__ gtp,
    const float* __restrict__ irp,
    const float* __restrict__ ivp, const float* __restrict__ ipp,
    unsigned int* __restrict__ counter, unsigned int* __restrict__ flags,
    float4* __restrict__ payload,
    float* __restrict__ out, int F, int cpb, int B)
{
  __shared__ int sTile;
  __shared__ St shw[NWAVE];
  __shared__ St chunkPrefSh;

  if (threadIdx.x == 0) sTile = (int)atomicAdd(counter, 1u);
  __syncthreads();

  const int t = sTile;
  const int b = t / cpb, c = t - b*cpb;
  const int tid = threadIdx.x;
  const int lane = tid & 63, wv = tid >> 6;
  const size_t gi = (size_t)b*F + (size_t)c*CHUNK + (size_t)tid*SEQ;

  BUILD_ELEMS(e);
  St incl = e[0];
  #pragma unroll
  for (int i = 1; i < SEQ; ++i) incl = combine(incl, e[i]);

  // wave inclusive scan (order-correct: left operand is the earlier segment)
  #pragma unroll
  for (int d = 1; d < 64; d <<= 1) {
    St o = shfl_up_st(incl, d);
    if (lane >= d) incl = combine(o, incl);
  }
  if (lane == 63) shw[wv] = incl;
  __syncthreads();

  if (wv == 0) {
    St bagg = combine(combine(shw[0], shw[1]), combine(shw[2], shw[3]));
    if (c == 0) {
      if (lane == 0) {
        St seed = identity_st();
        seed.q = { irp[b*4+0], irp[b*4+1], irp[b*4+2], irp[b*4+3] };
        st_st3(&payload[(size_t)t*3], combine(seed, bagg));
        __hip_atomic_store(&flags[t], 1u, __ATOMIC_RELEASE, __HIP_MEMORY_SCOPE_AGENT);
        chunkPrefSh = seed;
      }
    } else {
      if (lane == 0) {
        st_st3(&payload[(size_t)t*3], bagg);
        __hip_atomic_store(&flags[t], 1u, __ATOMIC_RELEASE, __HIP_MEMORY_SCOPE_AGENT);
      }
      // parallel lookback window over all predecessors in this row (cpb<=64)
      const int lo  = t - c;          // row-first tile
      const int idx = t - 1 - lane;   // lane's predecessor tile
      const bool valid = idx >= lo;
      unsigned int f = valid ? 0u : 1u;
      while (__any(f == 0u)) {
        if (f == 0u)
          f = __hip_atomic_load(&flags[idx], __ATOMIC_ACQUIRE, __HIP_MEMORY_SCOPE_AGENT);
        if (__any(f == 0u)) __builtin_amdgcn_s_sleep(2);
      }
      St X = identity_st();
      if (valid) X = ld_st3(&payload[(size_t)idx*3]);
      // flipped halving reduce: lane L holds tile t-1-L, so descending-lane
      // order == ascending-tile order; combine(o, X) keeps earlier on left.
      #pragma unroll
      for (int d = 1; d < 64; d <<= 1) X = combine(shfl_down_st(X, d), X);
      if (lane == 0) chunkPrefSh = X;   // exclusive prefix incl. seed
    }
  }
  __syncthreads();

  St P = chunkPrefSh;
  for (int k = 0; k < wv; ++k) P = combine(P, shw[k]);
  {
    St ex = shfl_up_st(incl, 1);
    if (lane > 0) P = combine(P, ex);
  }

  V3 iv = { ivp[b*3+0], ivp[b*3+1], ivp[b*3+2] };
  V3 ip = { ipp[b*3+0], ipp[b*3+1], ipp[b*3+2] };

  const size_t BF = (size_t)B * (size_t)F;
  float4* rot4 = (float4*)out;
  float4* vel4 = (float4*)(out + BF*4);
  float4* pos4 = (float4*)(out + BF*7);

  St run = P;
  float velb[SEQ*3], posb[SEQ*3];
  #pragma unroll
  for (int i = 0; i < SEQ; ++i) {
    run = combine(run, e[i]);
    rot4[gi + i] = make_float4(run.q.x, run.q.y, run.q.z, run.q.w);
    velb[3*i+0] = iv.x + run.s.x;
    velb[3*i+1] = iv.y + run.s.y;
    velb[3*i+2] = iv.z + run.s.z;
    posb[3*i+0] = ip.x + iv.x*run.T + run.p.x;
    posb[3*i+1] = ip.y + iv.y*run.T + run.p.y;
    posb[3*i+2] = ip.z + iv.z*run.T + run.p.z;
  }
  const size_t v0 = (gi*3) >> 2;
  #pragma unroll
  for (int j = 0; j < SEQ*3/4; ++j) {
    vel4[v0 + j] = ((float4*)velb)[j];
    pos4[v0 + j] = ((float4*)posb)[j];
  }
}

} // namespace

extern "C" void kernel_launch(void* const* d_in, const int* in_sizes, int n_in,
                              void* d_out, int out_size, void* d_ws, size_t ws_size,
                              hipStream_t stream)
{
  (void)n_in; (void)out_size; (void)ws_size;

  const float* dtp = (const float*)d_in[0];
  const float* gyp = (const float*)d_in[1];
  const float* acp = (const float*)d_in[2];
  const float* gtp = (const float*)d_in[3];
  const float* irp = (const float*)d_in[4];
  const float* ivp = (const float*)d_in[5];
  const float* ipp = (const float*)d_in[6];
  float* out = (float*)d_out;

  const int B   = in_sizes[4] / 4;        // init_rot has B*4 elements
  const int F   = in_sizes[0] / B;        // dt has B*F elements
  const int cpb = F / CHUNK;              // 32 for F=32768 (must be <= 64)
  const int nblk = B * cpb;               // 2048

  // workspace layout: counter @0 (pad to 128) | flags nblk*u32 | payload nblk*48B
  unsigned int* counter = (unsigned int*)d_ws;
  unsigned int* flags   = (unsigned int*)((char*)d_ws + 128);
  const size_t flagsBytes = (size_t)nblk * 4;
  float4* payload = (float4*)((char*)d_ws + 128 + ((flagsBytes + 127) & ~(size_t)127));

  hipMemsetAsync(d_ws, 0, 128 + ((flagsBytes + 127) & ~(size_t)127), stream);
  k_fused<<<nblk, BLK, 0, stream>>>(dtp, gyp, acp, gtp, irp, ivp, ipp,
                                    counter, flags, payload, out, F, cpb, B);
}

// Round 6
// 90.252 us; speedup vs baseline: 1.4784x; 1.4784x over previous
//
#include <hip/hip_runtime.h>
#include <math.h>

namespace {

constexpr int CHUNK = 512;          // elements per chunk (shared by both kernels)

constexpr int ABLK  = 128;          // k_agg: 128 threads x SEQ 4 = 512
constexpr int ASEQ  = 4;

constexpr int EBLK  = 256;          // k_emit: 256 threads x SEQ 2 = 512
constexpr int ESEQ  = 2;
constexpr int NWAVE = EBLK / 64;    // 4

struct V3 { float x, y, z; };
struct Q4 { float x, y, z, w; };
struct St { Q4 q; V3 s; V3 p; float T; float pad; }; // 48 B

__device__ __forceinline__ Q4 qmul(const Q4 a, const Q4 b) {
  Q4 r;
  r.x = a.w*b.x + b.w*a.x + a.y*b.z - a.z*b.y;
  r.y = a.w*b.y + b.w*a.y + a.z*b.x - a.x*b.z;
  r.z = a.w*b.z + b.w*a.z + a.x*b.y - a.y*b.x;
  r.w = a.w*b.w - a.x*b.x - a.y*b.y - a.z*b.z;
  return r;
}

__device__ __forceinline__ V3 qrot(const Q4 q, const V3 v) {
  float tx = q.y*v.z - q.z*v.y + q.w*v.x;
  float ty = q.z*v.x - q.x*v.z + q.w*v.y;
  float tz = q.x*v.y - q.y*v.x + q.w*v.z;
  V3 r;
  r.x = v.x + 2.0f*(q.y*tz - q.z*ty);
  r.y = v.y + 2.0f*(q.z*tx - q.x*tz);
  r.z = v.z + 2.0f*(q.x*ty - q.y*tx);
  return r;
}

__device__ __forceinline__ St combine(const St a, const St b) {
  St r;
  r.q = qmul(a.q, b.q);
  V3 rs = qrot(a.q, b.s);
  r.s.x = a.s.x + rs.x;
  r.s.y = a.s.y + rs.y;
  r.s.z = a.s.z + rs.z;
  V3 rp = qrot(a.q, b.p);
  r.p.x = a.p.x + a.s.x*b.T + rp.x;
  r.p.y = a.p.y + a.s.y*b.T + rp.y;
  r.p.z = a.p.z + a.s.z*b.T + rp.z;
  r.T = a.T + b.T;
  r.pad = 0.0f;
  return r;
}

__device__ __forceinline__ St identity_st() {
  St r;
  r.q = {0.0f, 0.0f, 0.0f, 1.0f};
  r.s = {0.0f, 0.0f, 0.0f};
  r.p = {0.0f, 0.0f, 0.0f};
  r.T = 0.0f; r.pad = 0.0f;
  return r;
}

// θ = |gyro*dt| ≤ ~0.02 here: 2-term Taylor in θ² is fp32-exact. No libm.
__device__ __forceinline__ St elem_state(float dt, V3 w, V3 ac, Q4 gt) {
  float px = w.x*dt, py = w.y*dt, pz = w.z*dt;
  float t2 = px*px + py*py + pz*pz;                        // θ²
  float k  = 0.5f + t2*(-1.0f/48.0f  + t2*(1.0f/3840.0f)); // sin(θ/2)/θ
  float cw = 1.0f + t2*(-0.125f      + t2*(1.0f/384.0f));  // cos(θ/2)
  Q4 dr = { px*k, py*k, pz*k, cw };
  Q4 gi = { -gt.x, -gt.y, -gt.z, gt.w };
  V3 g  = { 0.0f, 0.0f, 9.81007f };
  V3 gr = qrot(gi, g);
  V3 a  = { ac.x - gr.x, ac.y - gr.y, ac.z - gr.z };
  V3 ra = qrot(dr, a);
  St e;
  e.q = dr;
  e.s.x = ra.x*dt; e.s.y = ra.y*dt; e.s.z = ra.z*dt;
  float h = 0.5f*dt;
  e.p.x = e.s.x*h; e.p.y = e.s.y*h; e.p.z = e.s.z*h;
  e.T = dt; e.pad = 0.0f;
  return e;
}

__device__ __forceinline__ St shfl_up_st(const St& v, int d) {
  St r;
  r.q.x = __shfl_up(v.q.x, d); r.q.y = __shfl_up(v.q.y, d);
  r.q.z = __shfl_up(v.q.z, d); r.q.w = __shfl_up(v.q.w, d);
  r.s.x = __shfl_up(v.s.x, d); r.s.y = __shfl_up(v.s.y, d);
  r.s.z = __shfl_up(v.s.z, d);
  r.p.x = __shfl_up(v.p.x, d); r.p.y = __shfl_up(v.p.y, d);
  r.p.z = __shfl_up(v.p.z, d);
  r.T   = __shfl_up(v.T, d);   r.pad = 0.0f;
  return r;
}

__device__ __forceinline__ St shfl_down_st(const St& v, int d) {
  St r;
  r.q.x = __shfl_down(v.q.x, d); r.q.y = __shfl_down(v.q.y, d);
  r.q.z = __shfl_down(v.q.z, d); r.q.w = __shfl_down(v.q.w, d);
  r.s.x = __shfl_down(v.s.x, d); r.s.y = __shfl_down(v.s.y, d);
  r.s.z = __shfl_down(v.s.z, d);
  r.p.x = __shfl_down(v.p.x, d); r.p.y = __shfl_down(v.p.y, d);
  r.p.z = __shfl_down(v.p.z, d);
  r.T   = __shfl_down(v.T, d);   r.pad = 0.0f;
  return r;
}

// Kernel 1: per-chunk aggregates (CHUNK=512, 128 thr x 4 elems, float4 loads).
// combine is NON-COMMUTATIVE; shfl_down halving reduce is order-preserving
// (lane i merges segment [i,i+d) with [i+d,i+2d)).
__global__ __launch_bounds__(ABLK) void k_agg(
    const float* __restrict__ dtp, const float* __restrict__ gyp,
    const float* __restrict__ acp, const float* __restrict__ gtp,
    St* __restrict__ aggs, int F, int cpb)
{
  const int blk = blockIdx.x;
  const int b = blk / cpb, c = blk - b*cpb;
  const int tid = threadIdx.x;
  const int lane = tid & 63, wv = tid >> 6;
  const size_t gi = (size_t)b*F + (size_t)c*CHUNK + (size_t)tid*ASEQ;

  St e[ASEQ];
  {
    float dtv[ASEQ]; float gy[ASEQ*3]; float acv[ASEQ*3]; float gq[ASEQ*4];
    *((float4*)dtv) = *(const float4*)(dtp + gi);
    #pragma unroll
    for (int j = 0; j < 3; ++j) ((float4*)gy)[j]  = ((const float4*)(gyp + gi*3))[j];
    #pragma unroll
    for (int j = 0; j < 3; ++j) ((float4*)acv)[j] = ((const float4*)(acp + gi*3))[j];
    #pragma unroll
    for (int j = 0; j < 4; ++j) ((float4*)gq)[j]  = ((const float4*)(gtp + gi*4))[j];
    #pragma unroll
    for (int i = 0; i < ASEQ; ++i)
      e[i] = elem_state(dtv[i],
                 {gy[3*i], gy[3*i+1], gy[3*i+2]},
                 {acv[3*i], acv[3*i+1], acv[3*i+2]},
                 {gq[4*i], gq[4*i+1], gq[4*i+2], gq[4*i+3]});
  }
  St run = e[0];
  #pragma unroll
  for (int i = 1; i < ASEQ; ++i) run = combine(run, e[i]);

  #pragma unroll
  for (int d = 1; d < 64; d <<= 1) run = combine(run, shfl_down_st(run, d));

  __shared__ St sh[ABLK/64];
  if (lane == 0) sh[wv] = run;
  __syncthreads();
  if (tid == 0) aggs[blk] = combine(sh[0], sh[1]);
}

// Kernel 2: chunk prefix (wave 0 ordered reduce over preceding chunk aggs,
// load hoisted to overlap with input loads) + wave shuffle scan + emit.
__global__ __launch_bounds__(EBLK) void k_emit(
    const float* __restrict__ dtp, const float* __restrict__ gyp,
    const float* __restrict__ acp, const float* __restrict__ gtp,
    const St* __restrict__ aggs,
    const float* __restrict__ irp,
    const float* __restrict__ ivp, const float* __restrict__ ipp,
    float* __restrict__ out, int F, int cpb, int B)
{
  const int blk = blockIdx.x;
  const int b = blk / cpb, c = blk - b*cpb;
  const int tid = threadIdx.x;
  const int lane = tid & 63, wv = tid >> 6;
  const size_t gi = (size_t)b*F + (size_t)c*CHUNK + (size_t)tid*ESEQ;

  __shared__ St chunkPrefSh;
  __shared__ St shw[NWAVE];

  // hoisted: issue aggs gather first so its latency hides under elem/scan work
  St A = identity_st();
  if (wv == 0 && lane < c) A = aggs[(size_t)b*cpb + lane];   // cpb <= 64

  // inputs: ESEQ=2 -> float2 loads (8 B/lane), gt_rot float4 x2
  St e[ESEQ];
  {
    float dtv[ESEQ]; float gy[ESEQ*3]; float acv[ESEQ*3]; float gq[ESEQ*4];
    *((float2*)dtv) = *(const float2*)(dtp + gi);
    #pragma unroll
    for (int j = 0; j < 3; ++j) ((float2*)gy)[j]  = ((const float2*)(gyp + gi*3))[j];
    #pragma unroll
    for (int j = 0; j < 3; ++j) ((float2*)acv)[j] = ((const float2*)(acp + gi*3))[j];
    #pragma unroll
    for (int j = 0; j < 2; ++j) ((float4*)gq)[j]  = ((const float4*)(gtp + gi*4))[j];
    #pragma unroll
    for (int i = 0; i < ESEQ; ++i)
      e[i] = elem_state(dtv[i],
                 {gy[3*i], gy[3*i+1], gy[3*i+2]},
                 {acv[3*i], acv[3*i+1], acv[3*i+2]},
                 {gq[4*i], gq[4*i+1], gq[4*i+2], gq[4*i+3]});
  }

  St incl = e[0];
  #pragma unroll
  for (int i = 1; i < ESEQ; ++i) incl = combine(incl, e[i]);

  // wave inclusive scan (order-correct: left operand is the earlier segment)
  #pragma unroll
  for (int d = 1; d < 64; d <<= 1) {
    St o = shfl_up_st(incl, d);
    if (lane >= d) incl = combine(o, incl);
  }
  if (lane == 63) shw[wv] = incl;

  // wave 0: exclusive chunk prefix = seed(b) ∘ agg[0..c-1]
  if (wv == 0) {
    #pragma unroll
    for (int d = 1; d < 64; d <<= 1) A = combine(A, shfl_down_st(A, d));
    if (lane == 0) {
      St seed = identity_st();
      seed.q = { irp[b*4+0], irp[b*4+1], irp[b*4+2], irp[b*4+3] };
      chunkPrefSh = combine(seed, A);
    }
  }
  __syncthreads();

  St P = chunkPrefSh;
  for (int k = 0; k < wv; ++k) P = combine(P, shw[k]);
  {
    St ex = shfl_up_st(incl, 1);
    if (lane > 0) P = combine(P, ex);
  }

  V3 iv = { ivp[b*3+0], ivp[b*3+1], ivp[b*3+2] };
  V3 ip = { ipp[b*3+0], ipp[b*3+1], ipp[b*3+2] };

  const size_t BF = (size_t)B * (size_t)F;
  float4* rot4 = (float4*)out;
  float*  velp = out + BF*4;
  float*  posp = out + BF*7;

  St run = P;
  float velb[ESEQ*3], posb[ESEQ*3];
  #pragma unroll
  for (int i = 0; i < ESEQ; ++i) {
    run = combine(run, e[i]);
    rot4[gi + i] = make_float4(run.q.x, run.q.y, run.q.z, run.q.w);
    velb[3*i+0] = iv.x + run.s.x;
    velb[3*i+1] = iv.y + run.s.y;
    velb[3*i+2] = iv.z + run.s.z;
    posb[3*i+0] = ip.x + iv.x*run.T + run.p.x;
    posb[3*i+1] = ip.y + iv.y*run.T + run.p.y;
    posb[3*i+2] = ip.z + iv.z*run.T + run.p.z;
  }
  // 6 floats per thread -> 3x float2 (8 B aligned: gi even -> gi*3 even)
  #pragma unroll
  for (int j = 0; j < ESEQ*3/2; ++j) {
    ((float2*)(velp + gi*3))[j] = ((float2*)velb)[j];
    ((float2*)(posp + gi*3))[j] = ((float2*)posb)[j];
  }
}

} // namespace

extern "C" void kernel_launch(void* const* d_in, const int* in_sizes, int n_in,
                              void* d_out, int out_size, void* d_ws, size_t ws_size,
                              hipStream_t stream)
{
  (void)n_in; (void)out_size; (void)ws_size;

  const float* dtp = (const float*)d_in[0];
  const float* gyp = (const float*)d_in[1];
  const float* acp = (const float*)d_in[2];
  const float* gtp = (const float*)d_in[3];
  const float* irp = (const float*)d_in[4];
  const float* ivp = (const float*)d_in[5];
  const float* ipp = (const float*)d_in[6];
  float* out = (float*)d_out;

  const int B   = in_sizes[4] / 4;        // init_rot has B*4 elements
  const int F   = in_sizes[0] / B;        // dt has B*F elements
  const int cpb = F / CHUNK;              // 64 for F=32768 (must be <= 64)
  const int nblk = B * cpb;               // 4096

  St* aggs = (St*)d_ws;

  k_agg <<<nblk, ABLK, 0, stream>>>(dtp, gyp, acp, gtp, aggs, F, cpb);
  k_emit<<<nblk, EBLK, 0, stream>>>(dtp, gyp, acp, gtp, aggs, irp, ivp, ipp,
                                    out, F, cpb, B);
}